// Round 8
// baseline (522.050 us; speedup 1.0000x reference)
//
#include <hip/hip_runtime.h>
#include <hip/hip_bf16.h>
#include <math.h>

// Problem: B=8, N=2048, DIN=DOUT=512, adj binary p=0.01
// out = tanh( D^-1/2 (A v I) D^-1/2 (X W) + b )
//
// DIAGNOSTIC ROUND: each kernel repeats its (idempotent) body internally
// (scan x6, gemm x10, agg x8) so every dispatch exceeds the harness's 75us
// fillBuffers and surfaces in the top-5 WITH full PMC counters.
// Per-rep cost = dur_us / REP. Pipeline structure otherwise identical to R7.

#define NROWS 16384
#define NCOLS 2048
#define DF    512
#define CAP   64        // max edges/row (Binom(2048,0.01): mean ~21.5, P(>=64)~0)

#define SREP  6
#define GREP  10
#define AREP  8

typedef __attribute__((ext_vector_type(8))) short bf16x8;
typedef __attribute__((ext_vector_type(4))) float f32x4;
typedef const void __attribute__((address_space(1))) gvoid_t;
typedef void __attribute__((address_space(3))) svoid_t;

// ---------------------------------------------------------------------------
// K1: W->WT | adj scan | X->bf16   (x SREP)
// ---------------------------------------------------------------------------
__global__ __launch_bounds__(256) void scan_rep(
    const float* __restrict__ W, __hip_bfloat16* __restrict__ WT,
    const float* __restrict__ adj, int* __restrict__ cnt,
    int* __restrict__ edges, float* __restrict__ dinv,
    const float* __restrict__ X, __hip_bfloat16* __restrict__ Xb) {
  __shared__ float t[64][65];
  const int blk = blockIdx.x;
  const int tid = threadIdx.x;
  for (int rep = 0; rep < SREP; ++rep) {
    if (blk < 64) {                                // W -> W^T bf16
      const int bx = blk & 7, by = blk >> 3;
      const int tx = tid & 63, ty = tid >> 6;
      #pragma unroll
      for (int i = 0; i < 16; ++i)
        t[ty + i * 4][tx] = W[(size_t)(by * 64 + ty + i * 4) * DF + bx * 64 + tx];
      __syncthreads();
      #pragma unroll
      for (int i = 0; i < 16; ++i)                 // WT[n][k] = W[k][n]
        WT[(size_t)(bx * 64 + ty + i * 4) * DF + by * 64 + tx] =
            __float2bfloat16(t[tx][ty + i * 4]);
      __syncthreads();                             // WAR guard for next rep
    } else if (blk >= 1088) {                      // X -> bf16 (coalesced)
      const int b = blk - 1088;                    // 0..2047
      const float4* X4 = (const float4*)X;
      ushort4* O4 = (ushort4*)Xb;
      #pragma unroll
      for (int i = 0; i < 4; ++i) {
        const int idx = b * 1024 + i * 256 + tid;
        const float4 v = X4[idx];
        union { ushort4 u; __hip_bfloat16 h[4]; } p;
        p.h[0] = __float2bfloat16(v.x);
        p.h[1] = __float2bfloat16(v.y);
        p.h[2] = __float2bfloat16(v.z);
        p.h[3] = __float2bfloat16(v.w);
        O4[idx] = p.u;
      }
    } else {                                       // adjacency scan
      const int lane = tid & 63;
      const int wv = tid >> 6;
      const int rbase = (blk - 64) * 16 + wv * 4;
      float4 cur[8], nxt[8];
      {
        const float4* r4 = (const float4*)(adj + (size_t)rbase * NCOLS);
        #pragma unroll
        for (int k = 0; k < 8; ++k) cur[k] = r4[k * 64 + lane];
      }
      #pragma unroll
      for (int g = 0; g < 4; ++g) {
        const int r = rbase + g;
        if (g < 3) {
          const float4* rn = (const float4*)(adj + (size_t)(r + 1) * NCOLS);
          #pragma unroll
          for (int k = 0; k < 8; ++k) nxt[k] = rn[k * 64 + lane];
        }
        const int n = r & (NCOLS - 1);
        unsigned m = 0;
        #pragma unroll
        for (int k = 0; k < 8; ++k) {
          m |= (cur[k].x != 0.0f ? 1u : 0u) << (4 * k);
          m |= (cur[k].y != 0.0f ? 1u : 0u) << (4 * k + 1);
          m |= (cur[k].z != 0.0f ? 1u : 0u) << (4 * k + 2);
          m |= (cur[k].w != 0.0f ? 1u : 0u) << (4 * k + 3);
        }
        if (lane == ((n >> 2) & 63))               // force self-loop bit
          m |= 1u << (((n >> 8) << 2) | (n & 3));
        const int c_ = __popc(m);
        int inc = c_;                              // inclusive wave prefix-scan
        #pragma unroll
        for (int off = 1; off < 64; off <<= 1) {
          const int tv = __shfl_up(inc, off);
          if (lane >= off) inc += tv;
        }
        const int tot = __shfl(inc, 63);
        int p = inc - c_;                          // exclusive prefix
        unsigned mm = m;
        const size_t eb = (size_t)r * CAP;
        while (mm) {                               // <= ~3 iters per lane
          const int bpos = __ffs(mm) - 1;
          mm &= mm - 1;
          if (p < CAP)
            edges[eb + p] = ((bpos >> 2) << 8) + (lane << 2) + (bpos & 3);
          ++p;
        }
        if (lane == 63) {
          cnt[r] = tot < CAP ? tot : CAP;
          dinv[r] = rsqrtf((float)tot);            // deg >= 1 (self-loop)
        }
        #pragma unroll
        for (int k = 0; k < 8; ++k) cur[k] = nxt[k];
      }
    }
    asm volatile("" ::: "memory");                 // block cross-rep elision
  }
}

// ---------------------------------------------------------------------------
// K2: H = Xb @ WT^T  (x GREP). 128x128, BK=32, dbuf, global_load_lds both.
// ---------------------------------------------------------------------------
__global__ __launch_bounds__(256) void gemm_rep(
    const __hip_bfloat16* __restrict__ A, const __hip_bfloat16* __restrict__ BT,
    __hip_bfloat16* __restrict__ H) {
  __shared__ __hip_bfloat16 As[2][128 * 32];
  __shared__ __hip_bfloat16 Bs[2][128 * 32];
  const int tid = threadIdx.x;
  const int lane = tid & 63;
  const int w = tid >> 6;
  const int id = blockIdx.x;
  const int xcd = id & 7;
  const int jj = id >> 3;
  const int bm = (xcd * 16 + (jj >> 2)) * 128;     // panel -> XCD pin
  const int bn = (jj & 3) * 128;

  const int wm = (w >> 1) * 64;
  const int wn = (w & 1) * 64;
  const int srow = tid >> 2;
  const int scol = (tid & 3) * 8;
  const int kl = (lane >> 4) * 8;
  const int rl = lane & 15;

  #define STAGE(k0, buf)  do {                                          \
    _Pragma("unroll")                                                   \
    for (int i = 0; i < 2; ++i) {                                       \
      const __hip_bfloat16* ga = A  + (size_t)(bm + i * 64 + srow) * DF + (k0) + scol; \
      const __hip_bfloat16* gb = BT + (size_t)(bn + i * 64 + srow) * DF + (k0) + scol; \
      char* la = (char*)&As[buf][0] + i * 4096 + w * 1024;              \
      char* lb = (char*)&Bs[buf][0] + i * 4096 + w * 1024;              \
      __builtin_amdgcn_global_load_lds((gvoid_t*)ga, (svoid_t*)la, 16, 0, 0); \
      __builtin_amdgcn_global_load_lds((gvoid_t*)gb, (svoid_t*)lb, 16, 0, 0); \
    } } while (0)

  for (int rep = 0; rep < GREP; ++rep) {
    f32x4 acc[4][4] = {};
    STAGE(0, 0);
    __syncthreads();
    for (int tIt = 0; tIt < 16; ++tIt) {
      const int c_ = tIt & 1, nx = c_ ^ 1;
      if (tIt < 15) STAGE((tIt + 1) * 32, nx);
      bf16x8 af[4], bf[4];
      #pragma unroll
      for (int mi = 0; mi < 4; ++mi)
        af[mi] = *(const bf16x8*)&As[c_][(wm + mi * 16 + rl) * 32 + kl];
      #pragma unroll
      for (int ni = 0; ni < 4; ++ni)
        bf[ni] = *(const bf16x8*)&Bs[c_][(wn + ni * 16 + rl) * 32 + kl];
      #pragma unroll
      for (int mi = 0; mi < 4; ++mi)
        #pragma unroll
        for (int ni = 0; ni < 4; ++ni)
          acc[mi][ni] = __builtin_amdgcn_mfma_f32_16x16x32_bf16(af[mi], bf[ni], acc[mi][ni], 0, 0, 0);
      __syncthreads();
    }
    const int rq = (lane >> 4) * 4;                // D: col=lane&15, row=rq+j
    #pragma unroll
    for (int mi = 0; mi < 4; ++mi)
      #pragma unroll
      for (int ni = 0; ni < 4; ++ni) {
        const int col = bn + wn + ni * 16 + rl;
        #pragma unroll
        for (int j = 0; j < 4; ++j) {
          const int row = bm + wm + mi * 16 + rq + j;
          H[(size_t)row * DF + col] = __float2bfloat16(acc[mi][ni][j]);
        }
      }
    asm volatile("" ::: "memory");
    __syncthreads();                               // LDS WAR guard for next rep
  }
  #undef STAGE
}

// ---------------------------------------------------------------------------
// K3: aggregate (x AREP). 2 rows/wave, chunk-4 gathers, batch->XCD pin.
// ---------------------------------------------------------------------------
__global__ __launch_bounds__(256) void agg_rep(
    const __hip_bfloat16* __restrict__ h, const int* __restrict__ cnt,
    const int* __restrict__ edges, const float* __restrict__ dinv,
    const float* __restrict__ bias, float* __restrict__ out) {
  const int lane = threadIdx.x & 63;
  const int wv = threadIdx.x >> 6;
  const int batch = blockIdx.x & 7;                // -> XCD pin
  const int qb = blockIdx.x >> 3;
  for (int rep = 0; rep < AREP; ++rep) {
    const int r0n = qb * 8 + wv * 2;
    const int r0 = (batch << 11) + r0n;
    const int r1 = r0 + 1;
    const float* dv = dinv + (batch << 11);
    const uint4* hbase = (const uint4*)(h + (size_t)(batch << 11) * DF);

    const int c0 = cnt[r0], c1 = cnt[r1];
    int   ml0 = 0, ml1 = 0;
    float wl0 = 0.0f, wl1 = 0.0f;
    if (lane < c0) { ml0 = edges[(size_t)r0 * CAP + lane]; wl0 = dv[ml0]; }
    if (lane < c1) { ml1 = edges[(size_t)r1 * CAP + lane]; wl1 = dv[ml1]; }

    float a0[8] = {0.f,0.f,0.f,0.f,0.f,0.f,0.f,0.f};
    float a1[8] = {0.f,0.f,0.f,0.f,0.f,0.f,0.f,0.f};
    const int cmax = c0 > c1 ? c0 : c1;
    for (int e = 0; e < cmax; e += 4) {
      uint4 v0[4], v1[4];
      #pragma unroll
      for (int j = 0; j < 4; ++j) {
        if (e + j < c0) v0[j] = hbase[(size_t)__shfl(ml0, e + j) * 64 + lane];
        if (e + j < c1) v1[j] = hbase[(size_t)__shfl(ml1, e + j) * 64 + lane];
      }
      #pragma unroll
      for (int j = 0; j < 4; ++j) {
        if (e + j < c0) {
          const float wt = __shfl(wl0, e + j);
          a0[0] += wt * __uint_as_float(v0[j].x << 16);
          a0[1] += wt * __uint_as_float(v0[j].x & 0xffff0000u);
          a0[2] += wt * __uint_as_float(v0[j].y << 16);
          a0[3] += wt * __uint_as_float(v0[j].y & 0xffff0000u);
          a0[4] += wt * __uint_as_float(v0[j].z << 16);
          a0[5] += wt * __uint_as_float(v0[j].z & 0xffff0000u);
          a0[6] += wt * __uint_as_float(v0[j].w << 16);
          a0[7] += wt * __uint_as_float(v0[j].w & 0xffff0000u);
        }
        if (e + j < c1) {
          const float wt = __shfl(wl1, e + j);
          a1[0] += wt * __uint_as_float(v1[j].x << 16);
          a1[1] += wt * __uint_as_float(v1[j].x & 0xffff0000u);
          a1[2] += wt * __uint_as_float(v1[j].y << 16);
          a1[3] += wt * __uint_as_float(v1[j].y & 0xffff0000u);
          a1[4] += wt * __uint_as_float(v1[j].z << 16);
          a1[5] += wt * __uint_as_float(v1[j].z & 0xffff0000u);
          a1[6] += wt * __uint_as_float(v1[j].w << 16);
          a1[7] += wt * __uint_as_float(v1[j].w & 0xffff0000u);
        }
      }
    }
    const float4* b4 = (const float4*)bias;
    const float4 bb0 = b4[lane * 2];
    const float4 bb1 = b4[lane * 2 + 1];
    const float dn0 = dv[r0n], dn1 = dv[r0n + 1];
    float4 o;
    float* op0 = out + (size_t)r0 * DF + lane * 8;
    o.x = tanhf(a0[0] * dn0 + bb0.x); o.y = tanhf(a0[1] * dn0 + bb0.y);
    o.z = tanhf(a0[2] * dn0 + bb0.z); o.w = tanhf(a0[3] * dn0 + bb0.w);
    *(float4*)op0 = o;
    o.x = tanhf(a0[4] * dn0 + bb1.x); o.y = tanhf(a0[5] * dn0 + bb1.y);
    o.z = tanhf(a0[6] * dn0 + bb1.z); o.w = tanhf(a0[7] * dn0 + bb1.w);
    *(float4*)(op0 + 4) = o;
    float* op1 = out + (size_t)r1 * DF + lane * 8;
    o.x = tanhf(a1[0] * dn1 + bb0.x); o.y = tanhf(a1[1] * dn1 + bb0.y);
    o.z = tanhf(a1[2] * dn1 + bb0.z); o.w = tanhf(a1[3] * dn1 + bb0.w);
    *(float4*)op1 = o;
    o.x = tanhf(a1[4] * dn1 + bb1.x); o.y = tanhf(a1[5] * dn1 + bb1.y);
    o.z = tanhf(a1[6] * dn1 + bb1.z); o.w = tanhf(a1[7] * dn1 + bb1.w);
    *(float4*)(op1 + 4) = o;
    asm volatile("" ::: "memory");
  }
}

// ---------------------------------------------------------------------------
extern "C" void kernel_launch(void* const* d_in, const int* in_sizes, int n_in,
                              void* d_out, int out_size, void* d_ws, size_t ws_size,
                              hipStream_t stream) {
  const float* X    = (const float*)d_in[0];   // [8,2048,512]
  const float* adj  = (const float*)d_in[1];   // [8,2048,2048]
  const float* W    = (const float*)d_in[2];   // [512,512]
  const float* bias = (const float*)d_in[3];   // [512]
  float* out = (float*)d_out;

  char* ws = (char*)d_ws;
  __hip_bfloat16* h    = (__hip_bfloat16*)(ws);                    // 16,777,216 B
  __hip_bfloat16* WT   = (__hip_bfloat16*)(ws + 16777216);         //    524,288 B
  float*          dinv = (float*)(ws + 17301504);                  //     65,536 B
  int*            cnt  = (int*)  (ws + 17367040);                  //     65,536 B
  int*            edges= (int*)  (ws + 17432576);                  //  4,194,304 B
  __hip_bfloat16* Xb   = (__hip_bfloat16*)(ws + 21626880);         // 16,777,216 B
  // total ws: 38,404,096 B

  scan_rep<<<3136, 256, 0, stream>>>(W, WT, adj, cnt, edges, dinv, X, Xb);
  gemm_rep<<<512, 256, 0, stream>>>(Xb, WT, h);
  agg_rep<<<2048, 256, 0, stream>>>(h, cnt, edges, dinv, bias, out);
}

// Round 9
// 72.547 us; speedup vs baseline: 7.1961x; 7.1961x over previous
//
#include <hip/hip_runtime.h>
#include <hip/hip_bf16.h>
#include <math.h>

// Problem: B=8, N=2048, DIN=DOUT=512, adj binary p=0.01
// out = tanh( D^-1/2 (A v I) D^-1/2 (X W) + b )
//
//   K1 scan_wt_cvt : blk[0,64)=W->WT bf16; blk[64,1088)=adj scan; blk[1088,3136)=X->bf16
//   K2 gemm_k      : H = Xb @ WT^T, bf16 MFMA 128x128, BK=32, dbuf, DMA staging
//   K3 aggregate   : 1 row/wave, 8-edge chunks, broadcast (same-address) loads
//                    for edge index + weight (NO shfl/bpermute on the address
//                    path), fast exp-based tanh, batch -> XCD pin.
// Measured (R8 decomposition): scan 16us, gemm 15.5us, agg was 33.7us.

#define NROWS 16384
#define NCOLS 2048
#define DF    512
#define CAP   64        // max edges/row (Binom(2048,0.01): mean ~21.5, P(>=64)~0)

typedef __attribute__((ext_vector_type(8))) short bf16x8;
typedef __attribute__((ext_vector_type(4))) float f32x4;
typedef const void __attribute__((address_space(1))) gvoid_t;
typedef void __attribute__((address_space(3))) svoid_t;

// ---------------------------------------------------------------------------
// K1: W->WT | adj scan | X->bf16
// ---------------------------------------------------------------------------
__global__ __launch_bounds__(256) void scan_wt_cvt(
    const float* __restrict__ W, __hip_bfloat16* __restrict__ WT,
    const float* __restrict__ adj, int* __restrict__ cnt,
    int* __restrict__ edges, float* __restrict__ dinv,
    const float* __restrict__ X, __hip_bfloat16* __restrict__ Xb) {
  __shared__ float t[64][65];
  const int blk = blockIdx.x;
  const int tid = threadIdx.x;
  if (blk < 64) {                                  // W -> W^T bf16
    const int bx = blk & 7, by = blk >> 3;
    const int tx = tid & 63, ty = tid >> 6;
    #pragma unroll
    for (int i = 0; i < 16; ++i)
      t[ty + i * 4][tx] = W[(size_t)(by * 64 + ty + i * 4) * DF + bx * 64 + tx];
    __syncthreads();
    #pragma unroll
    for (int i = 0; i < 16; ++i)                   // WT[n][k] = W[k][n]
      WT[(size_t)(bx * 64 + ty + i * 4) * DF + by * 64 + tx] =
          __float2bfloat16(t[tx][ty + i * 4]);
    return;
  }
  if (blk >= 1088) {                               // X -> bf16 (coalesced)
    const int b = blk - 1088;                      // 0..2047
    const float4* X4 = (const float4*)X;
    ushort4* O4 = (ushort4*)Xb;
    #pragma unroll
    for (int i = 0; i < 4; ++i) {
      const int idx = b * 1024 + i * 256 + tid;
      const float4 v = X4[idx];
      union { ushort4 u; __hip_bfloat16 h[4]; } p;
      p.h[0] = __float2bfloat16(v.x);
      p.h[1] = __float2bfloat16(v.y);
      p.h[2] = __float2bfloat16(v.z);
      p.h[3] = __float2bfloat16(v.w);
      O4[idx] = p.u;
    }
    return;
  }
  // adjacency scan: 16 rows per block, 4 rows per wave, 2-deep pipeline
  const int lane = tid & 63;
  const int wv = tid >> 6;
  const int rbase = (blk - 64) * 16 + wv * 4;
  float4 cur[8], nxt[8];
  {
    const float4* r4 = (const float4*)(adj + (size_t)rbase * NCOLS);
    #pragma unroll
    for (int k = 0; k < 8; ++k) cur[k] = r4[k * 64 + lane];
  }
  #pragma unroll
  for (int g = 0; g < 4; ++g) {
    const int r = rbase + g;
    if (g < 3) {
      const float4* rn = (const float4*)(adj + (size_t)(r + 1) * NCOLS);
      #pragma unroll
      for (int k = 0; k < 8; ++k) nxt[k] = rn[k * 64 + lane];
    }
    const int n = r & (NCOLS - 1);
    unsigned m = 0;
    #pragma unroll
    for (int k = 0; k < 8; ++k) {
      m |= (cur[k].x != 0.0f ? 1u : 0u) << (4 * k);
      m |= (cur[k].y != 0.0f ? 1u : 0u) << (4 * k + 1);
      m |= (cur[k].z != 0.0f ? 1u : 0u) << (4 * k + 2);
      m |= (cur[k].w != 0.0f ? 1u : 0u) << (4 * k + 3);
    }
    if (lane == ((n >> 2) & 63))                   // force self-loop bit
      m |= 1u << (((n >> 8) << 2) | (n & 3));
    const int c_ = __popc(m);
    int inc = c_;                                  // inclusive wave prefix-scan
    #pragma unroll
    for (int off = 1; off < 64; off <<= 1) {
      const int tv = __shfl_up(inc, off);
      if (lane >= off) inc += tv;
    }
    const int tot = __shfl(inc, 63);
    int p = inc - c_;                              // exclusive prefix
    unsigned mm = m;
    const size_t eb = (size_t)r * CAP;
    while (mm) {                                   // <= ~3 iters per lane
      const int bpos = __ffs(mm) - 1;
      mm &= mm - 1;
      if (p < CAP)
        edges[eb + p] = ((bpos >> 2) << 8) + (lane << 2) + (bpos & 3);
      ++p;
    }
    if (lane == 63) {
      cnt[r] = tot < CAP ? tot : CAP;
      dinv[r] = rsqrtf((float)tot);                // deg >= 1 (self-loop)
    }
    #pragma unroll
    for (int k = 0; k < 8; ++k) cur[k] = nxt[k];
  }
}

// ---------------------------------------------------------------------------
// K2: H = Xb @ WT^T. 128x128 tile, BK=32, 4 waves (2x2), double-buffered LDS,
//     both operands via global_load_lds, one barrier per K-step.
// ---------------------------------------------------------------------------
__global__ __launch_bounds__(256) void gemm_k(
    const __hip_bfloat16* __restrict__ A, const __hip_bfloat16* __restrict__ BT,
    __hip_bfloat16* __restrict__ H) {
  __shared__ __hip_bfloat16 As[2][128 * 32];
  __shared__ __hip_bfloat16 Bs[2][128 * 32];
  const int tid = threadIdx.x;
  const int lane = tid & 63;
  const int w = tid >> 6;
  const int id = blockIdx.x;
  const int xcd = id & 7;
  const int jj = id >> 3;
  const int bm = (xcd * 16 + (jj >> 2)) * 128;     // panel -> XCD pin
  const int bn = (jj & 3) * 128;

  const int wm = (w >> 1) * 64;
  const int wn = (w & 1) * 64;
  const int srow = tid >> 2;
  const int scol = (tid & 3) * 8;
  const int kl = (lane >> 4) * 8;
  const int rl = lane & 15;

  f32x4 acc[4][4] = {};

  #define STAGE(k0, buf)  do {                                          \
    _Pragma("unroll")                                                   \
    for (int i = 0; i < 2; ++i) {                                       \
      const __hip_bfloat16* ga = A  + (size_t)(bm + i * 64 + srow) * DF + (k0) + scol; \
      const __hip_bfloat16* gb = BT + (size_t)(bn + i * 64 + srow) * DF + (k0) + scol; \
      char* la = (char*)&As[buf][0] + i * 4096 + w * 1024;              \
      char* lb = (char*)&Bs[buf][0] + i * 4096 + w * 1024;              \
      __builtin_amdgcn_global_load_lds((gvoid_t*)ga, (svoid_t*)la, 16, 0, 0); \
      __builtin_amdgcn_global_load_lds((gvoid_t*)gb, (svoid_t*)lb, 16, 0, 0); \
    } } while (0)

  STAGE(0, 0);
  __syncthreads();

  for (int tIt = 0; tIt < 16; ++tIt) {
    const int c_ = tIt & 1, nx = c_ ^ 1;
    if (tIt < 15) STAGE((tIt + 1) * 32, nx);       // prefetch next K-tile
    bf16x8 af[4], bf[4];
    #pragma unroll
    for (int mi = 0; mi < 4; ++mi)
      af[mi] = *(const bf16x8*)&As[c_][(wm + mi * 16 + rl) * 32 + kl];
    #pragma unroll
    for (int ni = 0; ni < 4; ++ni)
      bf[ni] = *(const bf16x8*)&Bs[c_][(wn + ni * 16 + rl) * 32 + kl];
    #pragma unroll
    for (int mi = 0; mi < 4; ++mi)
      #pragma unroll
      for (int ni = 0; ni < 4; ++ni)
        acc[mi][ni] = __builtin_amdgcn_mfma_f32_16x16x32_bf16(af[mi], bf[ni], acc[mi][ni], 0, 0, 0);
    __syncthreads();                               // drains next-tile DMA
  }

  const int rq = (lane >> 4) * 4;                  // D: col=lane&15, row=rq+j
  #pragma unroll
  for (int mi = 0; mi < 4; ++mi)
    #pragma unroll
    for (int ni = 0; ni < 4; ++ni) {
      const int col = bn + wn + ni * 16 + rl;
      #pragma unroll
      for (int j = 0; j < 4; ++j) {
        const int row = bm + wm + mi * 16 + rq + j;
        H[(size_t)row * DF + col] = __float2bfloat16(acc[mi][ni][j]);
      }
    }
  #undef STAGE
}

// ---------------------------------------------------------------------------
// fast tanh: 1 - 2/(e^{2x}+1). v_exp + fast-div; saturates correctly at +-inf.
// ---------------------------------------------------------------------------
__device__ __forceinline__ float fast_tanh(float x) {
  const float t = __expf(2.0f * x);
  return 1.0f - __fdividef(2.0f, t + 1.0f);
}

// ---------------------------------------------------------------------------
// K3: aggregate. 4096 blocks x 4 waves = 1 row/wave. batch = blk&7 -> XCD pin.
// Edge index + weight via wave-uniform broadcast loads (no shfl on the
// address path); 8 independent uint4 gathers in flight per chunk.
// ---------------------------------------------------------------------------
__global__ __launch_bounds__(256) void aggregate(
    const __hip_bfloat16* __restrict__ h, const int* __restrict__ cnt,
    const int* __restrict__ edges, const float* __restrict__ dinv,
    const float* __restrict__ bias, float* __restrict__ out) {
  const int lane = threadIdx.x & 63;
  const int wv = threadIdx.x >> 6;
  const int batch = blockIdx.x & 7;                // -> XCD pin
  const int qb = blockIdx.x >> 3;                  // 0..511
  const int rn = qb * 4 + wv;                      // row within batch
  const int r = (batch << 11) + rn;
  const int c = cnt[r];
  const float* dv = dinv + (batch << 11);
  const uint4* hbase = (const uint4*)(h + (size_t)(batch << 11) * DF);
  const int* eb = edges + (size_t)r * CAP;

  float acc[8] = {0.f,0.f,0.f,0.f,0.f,0.f,0.f,0.f};
  for (int e = 0; e < c; e += 8) {                 // wave-uniform chunks
    int   mj[8];
    float wj[8];
    uint4 vj[8];
    #pragma unroll
    for (int j = 0; j < 8; ++j)                    // 8 broadcast index loads
      if (e + j < c) mj[j] = eb[e + j];
    #pragma unroll
    for (int j = 0; j < 8; ++j)                    // weights + gathers in flight
      if (e + j < c) {
        wj[j] = dv[mj[j]];
        vj[j] = hbase[(size_t)mj[j] * 64 + lane];
      }
    #pragma unroll
    for (int j = 0; j < 8; ++j)
      if (e + j < c) {
        const float wt = wj[j];
        acc[0] += wt * __uint_as_float(vj[j].x << 16);
        acc[1] += wt * __uint_as_float(vj[j].x & 0xffff0000u);
        acc[2] += wt * __uint_as_float(vj[j].y << 16);
        acc[3] += wt * __uint_as_float(vj[j].y & 0xffff0000u);
        acc[4] += wt * __uint_as_float(vj[j].z << 16);
        acc[5] += wt * __uint_as_float(vj[j].z & 0xffff0000u);
        acc[6] += wt * __uint_as_float(vj[j].w << 16);
        acc[7] += wt * __uint_as_float(vj[j].w & 0xffff0000u);
      }
  }
  const float4* b4 = (const float4*)bias;
  const float4 bb0 = b4[lane * 2];
  const float4 bb1 = b4[lane * 2 + 1];
  const float dn = dv[rn];
  float4 o;
  float* op = out + (size_t)r * DF + lane * 8;
  o.x = fast_tanh(acc[0] * dn + bb0.x);
  o.y = fast_tanh(acc[1] * dn + bb0.y);
  o.z = fast_tanh(acc[2] * dn + bb0.z);
  o.w = fast_tanh(acc[3] * dn + bb0.w);
  *(float4*)op = o;
  o.x = fast_tanh(acc[4] * dn + bb1.x);
  o.y = fast_tanh(acc[5] * dn + bb1.y);
  o.z = fast_tanh(acc[6] * dn + bb1.z);
  o.w = fast_tanh(acc[7] * dn + bb1.w);
  *(float4*)(op + 4) = o;
}

// ---------------------------------------------------------------------------
extern "C" void kernel_launch(void* const* d_in, const int* in_sizes, int n_in,
                              void* d_out, int out_size, void* d_ws, size_t ws_size,
                              hipStream_t stream) {
  const float* X    = (const float*)d_in[0];   // [8,2048,512]
  const float* adj  = (const float*)d_in[1];   // [8,2048,2048]
  const float* W    = (const float*)d_in[2];   // [512,512]
  const float* bias = (const float*)d_in[3];   // [512]
  float* out = (float*)d_out;

  char* ws = (char*)d_ws;
  __hip_bfloat16* h    = (__hip_bfloat16*)(ws);                    // 16,777,216 B
  __hip_bfloat16* WT   = (__hip_bfloat16*)(ws + 16777216);         //    524,288 B
  float*          dinv = (float*)(ws + 17301504);                  //     65,536 B
  int*            cnt  = (int*)  (ws + 17367040);                  //     65,536 B
  int*            edges= (int*)  (ws + 17432576);                  //  4,194,304 B
  __hip_bfloat16* Xb   = (__hip_bfloat16*)(ws + 21626880);         // 16,777,216 B
  // total ws: 38,404,096 B

  scan_wt_cvt<<<3136, 256, 0, stream>>>(W, WT, adj, cnt, edges, dinv, X, Xb);
  gemm_k<<<512, 256, 0, stream>>>(Xb, WT, h);
  aggregate<<<4096, 256, 0, stream>>>(h, cnt, edges, dinv, bias, out);
}